// Round 1
// baseline (443.958 us; speedup 1.0000x reference)
//
#include <hip/hip_runtime.h>
#include <hip/hip_bf16.h>

#define N_PIX 16384
#define W_ 128

typedef __attribute__((ext_vector_type(8))) unsigned short ushort8_t;
typedef __attribute__((ext_vector_type(4))) unsigned short ushort4_t;
typedef __attribute__((ext_vector_type(8))) __bf16 bf16x8;
typedef __attribute__((ext_vector_type(4))) float f32x4;

__device__ inline float bf2f(unsigned short u) {
    return __uint_as_float(((unsigned)u) << 16);
}
__device__ inline unsigned short f2bf(float f) {
    __hip_bfloat16 h = __float2bfloat16(f);
    return *(unsigned short*)&h;
}

// ---------------------------------------------------------------------------
// pack f32 conv weights -> bf16 (run once per conv; 110592 elems = 108 blocks)
// ---------------------------------------------------------------------------
__global__ __launch_bounds__(256) void k_pack_w(
    const float* __restrict__ w, unsigned short* __restrict__ o)
{
    const int i = (blockIdx.x * 256 + threadIdx.x) * 4;
    float4 v = *(const float4*)(w + i);
    ushort4_t s;
    s[0] = f2bf(v.x); s[1] = f2bf(v.y); s[2] = f2bf(v.z); s[3] = f2bf(v.w);
    *(ushort4_t*)(o + i) = s;
}

// ---------------------------------------------------------------------------
// conv1x1 via bf16 MFMA, round 4: W read directly from global bf16 (L2-hot,
// 221 KB). LDS = X tile only (64 pix x 192ch, padded to 200 => 25.6 KB).
// Grid (256,4); 3 blocks/CU -> 12 waves/CU (was 1 block / 4 waves at 125 KB).
// Each wave: M=48 W-rows x N=64 pixels; 3 passes cover 576 output rows.
// ---------------------------------------------------------------------------
__global__ __launch_bounds__(256, 3) void k_conv_mfma(
    const float* __restrict__ in,            // [4][192][N_PIX] f32
    const unsigned short* __restrict__ wbf,  // [576][192] bf16
    unsigned short* __restrict__ out)        // [4][576][N_PIX] bf16
{
    const int p0 = blockIdx.x * 64;
    const int b  = blockIdx.y;
    const float* inb = in + (long)b * 192 * N_PIX;
    unsigned short* ob = out + (long)b * 576 * N_PIX;

    __shared__ unsigned short Xl[64 * 200];

    const int tid  = threadIdx.x;
    const int lane = tid & 63;
    const int wid  = tid >> 6;
    const int l15  = lane & 15;
    const int lq   = lane >> 4;

    {   // stage X tile transposed [p][k], f32 -> bf16
        const int p = tid & 63, kg = tid >> 6;   // 4 channel-groups of 48
        #pragma unroll
        for (int seg = 0; seg < 6; seg++) {
            ushort8_t pk;
            #pragma unroll
            for (int j = 0; j < 8; j++)
                pk[j] = f2bf(inb[(long)(kg * 48 + seg * 8 + j) * N_PIX + p0 + p]);
            *(ushort8_t*)&Xl[p * 200 + kg * 48 + seg * 8] = pk;
        }
    }
    __syncthreads();

    #pragma unroll 1
    for (int oc = 0; oc < 3; oc++) {
        f32x4 acc[3][4];
        const f32x4 zero = {0.f, 0.f, 0.f, 0.f};
        #pragma unroll
        for (int i = 0; i < 3; i++)
            #pragma unroll
            for (int j = 0; j < 4; j++) acc[i][j] = zero;

        #pragma unroll
        for (int kc = 0; kc < 6; kc++) {
            bf16x8 af[3], bfv[4];
            #pragma unroll
            for (int mt = 0; mt < 3; mt++)
                af[mt] = *(const bf16x8*)(wbf +
                    (long)(oc * 192 + wid * 48 + mt * 16 + l15) * 192 + kc * 32 + lq * 8);
            #pragma unroll
            for (int nt = 0; nt < 4; nt++)
                bfv[nt] = *(const bf16x8*)&Xl[(nt * 16 + l15) * 200 + kc * 32 + lq * 8];
            #pragma unroll
            for (int mt = 0; mt < 3; mt++)
                #pragma unroll
                for (int nt = 0; nt < 4; nt++)
                    acc[mt][nt] = __builtin_amdgcn_mfma_f32_16x16x32_bf16(
                        af[mt], bfv[nt], acc[mt][nt], 0, 0, 0);
        }
        #pragma unroll
        for (int mt = 0; mt < 3; mt++) {
            #pragma unroll
            for (int r = 0; r < 4; r++) {
                int o = oc * 192 + wid * 48 + mt * 16 + lq * 4 + r;
                long base = (long)o * N_PIX + p0 + l15;
                #pragma unroll
                for (int nt = 0; nt < 4; nt++)
                    ob[base + nt * 16] = f2bf(acc[mt][nt][r]);
            }
        }
    }
}

// ---------------------------------------------------------------------------
// depthwise 3x3, pad 1, bf16 -> bf16, vectorized (unchanged):
// block = 16 rows x 128 cols of one map; 18x128 halo staged in LDS;
// each thread computes 8 contiguous pixels. grid (8 row-groups, 2304 maps).
// ---------------------------------------------------------------------------
__global__ __launch_bounds__(256) void k_dwconv(
    const unsigned short* __restrict__ in, const float* __restrict__ w,
    unsigned short* __restrict__ out)
{
    const int m  = blockIdx.y;              // b*576 + ch
    const int ch = m % 576;
    const int y0 = blockIdx.x * 16;
    const unsigned short* ip = in + (long)m * N_PIX;
    const float* wp = w + ch * 9;

    __shared__ unsigned short Ll[18][136];

    const int tid = threadIdx.x;
    #pragma unroll
    for (int idx = tid; idx < 288; idx += 256) {
        int lr = idx >> 4, lc = (idx & 15) * 8;
        int gy = y0 - 1 + lr;
        ushort8_t v;
        #pragma unroll
        for (int j = 0; j < 8; j++) v[j] = 0;
        if ((unsigned)gy <= 127u)
            v = *(const ushort8_t*)(ip + gy * W_ + lc);
        *(ushort8_t*)&Ll[lr][lc] = v;
    }
    float wv[9];
    #pragma unroll
    for (int i = 0; i < 9; i++) wv[i] = wp[i];
    __syncthreads();

    const int r  = tid >> 4;           // output row within group
    const int xg = (tid & 15) * 8;     // first of 8 output cols

    float o[8];
    #pragma unroll
    for (int j = 0; j < 8; j++) o[j] = 0.f;

    #pragma unroll
    for (int dy = 0; dy < 3; dy++) {
        const unsigned short* lrow = &Ll[r + dy][0];
        float c[10];
        c[0] = (xg == 0) ? 0.f : bf2f(lrow[xg - 1]);
        ushort8_t mid = *(const ushort8_t*)&lrow[xg];
        #pragma unroll
        for (int j = 0; j < 8; j++) c[1 + j] = bf2f(mid[j]);
        c[9] = (xg == 120) ? 0.f : bf2f(lrow[xg + 8]);
        const float w0 = wv[dy * 3], w1 = wv[dy * 3 + 1], w2 = wv[dy * 3 + 2];
        #pragma unroll
        for (int j = 0; j < 8; j++)
            o[j] = fmaf(w0, c[j], fmaf(w1, c[j + 1], fmaf(w2, c[j + 2], o[j])));
    }
    ushort8_t res;
    #pragma unroll
    for (int j = 0; j < 8; j++) res[j] = f2bf(o[j]);
    *(ushort8_t*)(out + (long)m * N_PIX + (y0 + r) * W_ + xg) = res;
}

// ---------------------------------------------------------------------------
// gram + norms via MFMA (unchanged)
// ---------------------------------------------------------------------------
__global__ __launch_bounds__(256) void k_gram_mfma(
    const unsigned short* __restrict__ qkv_x,
    const unsigned short* __restrict__ qkv_c,
    float* __restrict__ S, float* __restrict__ qn, float* __restrict__ kn)
{
    const int attn = blockIdx.z;
    const int bh   = blockIdx.y;
    const int b = bh >> 2, h = bh & 3;
    const unsigned short* qb =
        (attn == 0 ? qkv_x : qkv_c) + ((long)b * 576 + h * 48) * N_PIX;
    const unsigned short* kb =
        (attn == 0 ? qkv_c : qkv_x) + ((long)b * 576 + 192 + h * 48) * N_PIX;

    __shared__ float Sl[48 * 49];
    __shared__ float qnl[48], knl[48];

    const int tid = threadIdx.x;
    for (int i = tid; i < 48 * 49; i += 256) Sl[i] = 0.f;
    if (tid < 48) { qnl[tid] = 0.f; knl[tid] = 0.f; }
    __syncthreads();

    const int lane = tid & 63, wid = tid >> 6;
    const int l15 = lane & 15, lq = lane >> 4;
    const long nbase = (long)blockIdx.x * 1024 + wid * 256;

    f32x4 acc[3][3], aq[3], ak[3];
    const f32x4 zero = {0.f, 0.f, 0.f, 0.f};
    #pragma unroll
    for (int i = 0; i < 3; i++) {
        aq[i] = zero; ak[i] = zero;
        #pragma unroll
        for (int j = 0; j < 3; j++) acc[i][j] = zero;
    }

    for (int ks = 0; ks < 8; ks++) {
        const long ns = nbase + ks * 32;
        bf16x8 af[3], bfv[3];
        #pragma unroll
        for (int mt = 0; mt < 3; mt++)
            af[mt] = *(const bf16x8*)(qb + (long)(mt * 16 + l15) * N_PIX + ns + lq * 8);
        #pragma unroll
        for (int nt = 0; nt < 3; nt++)
            bfv[nt] = *(const bf16x8*)(kb + (long)(nt * 16 + l15) * N_PIX + ns + lq * 8);
        #pragma unroll
        for (int mt = 0; mt < 3; mt++)
            #pragma unroll
            for (int nt = 0; nt < 3; nt++)
                acc[mt][nt] = __builtin_amdgcn_mfma_f32_16x16x32_bf16(
                    af[mt], bfv[nt], acc[mt][nt], 0, 0, 0);
        #pragma unroll
        for (int mt = 0; mt < 3; mt++)
            aq[mt] = __builtin_amdgcn_mfma_f32_16x16x32_bf16(af[mt], af[mt], aq[mt], 0, 0, 0);
        #pragma unroll
        for (int nt = 0; nt < 3; nt++)
            ak[nt] = __builtin_amdgcn_mfma_f32_16x16x32_bf16(bfv[nt], bfv[nt], ak[nt], 0, 0, 0);
    }

    #pragma unroll
    for (int mt = 0; mt < 3; mt++)
        #pragma unroll
        for (int nt = 0; nt < 3; nt++)
            #pragma unroll
            for (int r = 0; r < 4; r++)
                atomicAdd(&Sl[(mt * 16 + lq * 4 + r) * 49 + nt * 16 + l15],
                          acc[mt][nt][r]);
    #pragma unroll
    for (int mt = 0; mt < 3; mt++)
        #pragma unroll
        for (int r = 0; r < 4; r++)
            if (l15 == lq * 4 + r) {
                atomicAdd(&qnl[mt * 16 + l15], aq[mt][r]);
                atomicAdd(&knl[mt * 16 + l15], ak[mt][r]);
            }
    __syncthreads();

    float* Sg = S + (long)(attn * 16 + bh) * 2304;
    float* qg = qn + (long)(attn * 16 + bh) * 48;
    float* kg = kn + (long)(attn * 16 + bh) * 48;
    for (int i = tid; i < 2304; i += 256) {
        int row = i / 48, col = i - row * 48;
        atomicAdd(&Sg[i], Sl[row * 49 + col]);
    }
    if (tid < 48) atomicAdd(&qg[tid], qnl[tid]);
    else if (tid < 96) atomicAdd(&kg[tid - 48], knl[tid - 48]);
}

// ---------------------------------------------------------------------------
// softmax (unchanged)
// ---------------------------------------------------------------------------
__global__ __launch_bounds__(192) void k_softmax(
    const float* __restrict__ S, const float* __restrict__ qn,
    const float* __restrict__ kn, const float* __restrict__ temp,
    float* __restrict__ P)
{
    const int attn = blockIdx.x, b = blockIdx.y;
    const int r = threadIdx.x;
    const int h = r / 48, c = r % 48;
    const int bh = b * 4 + h;
    const float t = temp[h];
    const float* Srow = S + ((long)(attn * 16 + bh) * 48 + c) * 48;
    const float* knp  = kn + (long)(attn * 16 + bh) * 48;
    const float qc = fmaxf(sqrtf(qn[(long)(attn * 16 + bh) * 48 + c]), 1e-12f);
    float lg[48];
    float mx = -1e30f;
    #pragma unroll
    for (int d = 0; d < 48; d++) {
        float kd = fmaxf(sqrtf(knp[d]), 1e-12f);
        lg[d] = Srow[d] / (qc * kd) * t;
        mx = fmaxf(mx, lg[d]);
    }
    float sum = 0.f;
    #pragma unroll
    for (int d = 0; d < 48; d++) { lg[d] = __expf(lg[d] - mx); sum += lg[d]; }
    const float inv = 1.f / sum;
    float* Pp = P + (((long)(attn * 4 + b) * 4 + h) * 48 + c) * 48;
    #pragma unroll
    for (int d = 0; d < 48; d++) Pp[d] = lg[d] * inv;
}

// ---------------------------------------------------------------------------
// W2[attn][b][o][h*48+d] = sum_c po[o][h*48+c] * P[attn][b][h][c][d]  (bf16)
// ---------------------------------------------------------------------------
__global__ __launch_bounds__(192) void k_w2(
    const float* __restrict__ P, const float* __restrict__ x_po,
    const float* __restrict__ ctx_po, unsigned short* __restrict__ W2)
{
    const int h = blockIdx.x, b = blockIdx.y, attn = blockIdx.z;
    const float* po = (attn == 0) ? ctx_po : x_po;
    __shared__ float Pl[48][48];
    const float* Pp = P + ((long)(attn * 4 + b) * 4 + h) * 2304;
    for (int it = 0; it < 12; it++) {
        int idx = it * 192 + threadIdx.x;
        Pl[idx / 48][idx % 48] = Pp[idx];
    }
    __syncthreads();
    const int o = threadIdx.x;
    float acc[48];
    #pragma unroll
    for (int d = 0; d < 48; d++) acc[d] = 0.f;
    for (int c = 0; c < 48; c++) {
        float pv = po[(long)o * 192 + h * 48 + c];
        #pragma unroll
        for (int d = 0; d < 48; d++)
            acc[d] = fmaf(pv, Pl[c][d], acc[d]);
    }
    unsigned short* wp = W2 + ((long)(attn * 4 + b) * 192 + o) * 192 + h * 48;
    #pragma unroll
    for (int d = 0; d < 48; d++) wp[d] = f2bf(acc[d]);
}

// ---------------------------------------------------------------------------
// final GEMM via MFMA, round 4: same 64-pixel-tile restructure as conv.
// out[br][b][o][p] = sum_d W2bf[.][o][d] * v[d][p]; grid (256, 8).
// W2 read directly from global (73.7 KB, L2-hot); LDS = V tile only.
// ---------------------------------------------------------------------------
__global__ __launch_bounds__(256, 3) void k_gemm_v(
    const unsigned short* __restrict__ qkv_x,
    const unsigned short* __restrict__ qkv_c,
    const unsigned short* __restrict__ W2bf,   // [attn][b][192][192] bf16
    float* __restrict__ out)
{
    const int p0 = blockIdx.x * 64;
    const int z  = blockIdx.y;
    const int br = z >> 2, b = z & 3;
    const unsigned short* v =
        (br == 0 ? qkv_x : qkv_c) + (long)b * 576 * N_PIX + 384L * N_PIX;
    const unsigned short* wb =
        W2bf + ((long)((br == 0 ? 1 : 0) * 4 + b)) * 36864;
    float* ob = out + (long)br * 12582912 + (long)b * 192 * N_PIX;

    __shared__ unsigned short Xl[64 * 200];

    const int tid  = threadIdx.x;
    const int lane = tid & 63;
    const int wid  = tid >> 6;
    const int l15  = lane & 15;
    const int lq   = lane >> 4;

    {   // stage V tile transposed [p][k]
        const int p = tid & 63, kg = tid >> 6;
        #pragma unroll
        for (int seg = 0; seg < 6; seg++) {
            ushort8_t pk;
            #pragma unroll
            for (int j = 0; j < 8; j++)
                pk[j] = v[(long)(kg * 48 + seg * 8 + j) * N_PIX + p0 + p];
            *(ushort8_t*)&Xl[p * 200 + kg * 48 + seg * 8] = pk;
        }
    }
    __syncthreads();

    f32x4 acc[3][4];
    const f32x4 zero = {0.f, 0.f, 0.f, 0.f};
    #pragma unroll
    for (int i = 0; i < 3; i++)
        #pragma unroll
        for (int j = 0; j < 4; j++) acc[i][j] = zero;

    #pragma unroll
    for (int kc = 0; kc < 6; kc++) {
        bf16x8 af[3], bfv[4];
        #pragma unroll
        for (int mt = 0; mt < 3; mt++)
            af[mt] = *(const bf16x8*)(wb +
                (long)(wid * 48 + mt * 16 + l15) * 192 + kc * 32 + lq * 8);
        #pragma unroll
        for (int nt = 0; nt < 4; nt++)
            bfv[nt] = *(const bf16x8*)&Xl[(nt * 16 + l15) * 200 + kc * 32 + lq * 8];
        #pragma unroll
        for (int mt = 0; mt < 3; mt++)
            #pragma unroll
            for (int nt = 0; nt < 4; nt++)
                acc[mt][nt] = __builtin_amdgcn_mfma_f32_16x16x32_bf16(
                    af[mt], bfv[nt], acc[mt][nt], 0, 0, 0);
    }
    #pragma unroll
    for (int mt = 0; mt < 3; mt++) {
        #pragma unroll
        for (int r = 0; r < 4; r++) {
            int o = wid * 48 + mt * 16 + lq * 4 + r;
            long base = (long)o * N_PIX + p0 + l15;
            #pragma unroll
            for (int nt = 0; nt < 4; nt++)
                ob[base + nt * 16] = acc[mt][nt][r];
        }
    }
}

// ---------------------------------------------------------------------------
extern "C" void kernel_launch(void* const* d_in, const int* in_sizes, int n_in,
                              void* d_out, int out_size, void* d_ws, size_t ws_size,
                              hipStream_t stream) {
    (void)in_sizes; (void)n_in; (void)out_size; (void)ws_size;
    const float* x       = (const float*)d_in[0];
    const float* ctx     = (const float*)d_in[1];
    const float* x_qkv_w = (const float*)d_in[2];
    const float* x_dw_w  = (const float*)d_in[3];
    const float* x_po_w  = (const float*)d_in[4];
    const float* c_qkv_w = (const float*)d_in[5];
    const float* c_dw_w  = (const float*)d_in[6];
    const float* c_po_w  = (const float*)d_in[7];
    const float* temp    = (const float*)d_in[8];
    float* out = (float*)d_out;

    const long QKV = 37748736L;                  // 4*576*16384 elements
    unsigned short* qkv_x16 = (unsigned short*)d_ws;
    unsigned short* qkv_c16 = qkv_x16 + QKV;
    float* S  = (float*)(qkv_c16 + QKV);         // 2*16*48*48
    float* qn = S + 73728;
    float* kn = qn + 1536;
    float* P  = kn + 1536;
    unsigned short* W2bf = (unsigned short*)(P + 73728);   // 2*4*192*192 bf16

    hipMemsetAsync(S, 0, (73728 + 1536 + 1536) * sizeof(float), stream);

    // conv tmp (bf16) lives in d_out: fully overwritten by k_gemm_v afterwards.
    // packed bf16 conv weights live in the unused tail of d_out (75.5 MB used
    // by tmp16, 100.7 MB total; pack needs 0.44 MB; consumed before k_gemm_v).
    unsigned short* tmp16 = (unsigned short*)d_out;
    unsigned short* wx16  = (unsigned short*)d_out + QKV;
    unsigned short* wc16  = wx16 + 110592;

    k_pack_w<<<dim3(108), 256, 0, stream>>>(x_qkv_w, wx16);
    k_pack_w<<<dim3(108), 256, 0, stream>>>(c_qkv_w, wc16);

    k_conv_mfma<<<dim3(256, 4), 256, 0, stream>>>(x, wx16, tmp16);
    k_dwconv<<<dim3(8, 2304), 256, 0, stream>>>(tmp16, x_dw_w, qkv_x16);
    k_conv_mfma<<<dim3(256, 4), 256, 0, stream>>>(ctx, wc16, tmp16);
    k_dwconv<<<dim3(8, 2304), 256, 0, stream>>>(tmp16, c_dw_w, qkv_c16);

    k_gram_mfma<<<dim3(16, 16, 2), 256, 0, stream>>>(qkv_x16, qkv_c16, S, qn, kn);
    k_softmax<<<dim3(2, 4), dim3(192), 0, stream>>>(S, qn, kn, temp, P);
    k_w2<<<dim3(4, 4, 2), dim3(192), 0, stream>>>(P, x_po_w, c_po_w, W2bf);

    k_gemm_v<<<dim3(256, 8), 256, 0, stream>>>(qkv_x16, qkv_c16, W2bf, out);
}

// Round 2
// 398.327 us; speedup vs baseline: 1.1146x; 1.1146x over previous
//
#include <hip/hip_runtime.h>
#include <hip/hip_bf16.h>

#define N_PIX 16384
#define W_ 128

typedef __attribute__((ext_vector_type(8))) unsigned short ushort8_t;
typedef __attribute__((ext_vector_type(4))) unsigned short ushort4_t;
typedef __attribute__((ext_vector_type(8))) __bf16 bf16x8;
typedef __attribute__((ext_vector_type(4))) float f32x4;

__device__ inline float bf2f(unsigned short u) {
    return __uint_as_float(((unsigned)u) << 16);
}
__device__ inline unsigned short f2bf(float f) {
    __hip_bfloat16 h = __float2bfloat16(f);
    return *(unsigned short*)&h;
}

// async 16B global->LDS DMA (lane i lands at ldsbase + 16*i)
__device__ inline void glds16(const unsigned short* g, unsigned short* l) {
    __builtin_amdgcn_global_load_lds(
        (const __attribute__((address_space(1))) unsigned int*)g,
        (__attribute__((address_space(3))) unsigned int*)l, 16, 0, 0);
}

// ---------------------------------------------------------------------------
// pack f32 conv weights -> bf16, PRE-SWIZZLED for conflict-free ds_read_b128:
// within each row (192 bf16 = 24 x 16B chunks), chunk c stored at c ^ (row&7).
// 576*24 = 13824 chunks -> 54 blocks x 256 threads.
// ---------------------------------------------------------------------------
__global__ __launch_bounds__(256) void k_pack_w_swz(
    const float* __restrict__ w, unsigned short* __restrict__ o)
{
    const int idx = blockIdx.x * 256 + threadIdx.x;
    const int row = idx / 24, c = idx % 24;
    const int sc = c ^ (row & 7);
    const float* src = w + (long)row * 192 + c * 8;
    ushort8_t s;
    #pragma unroll
    for (int j = 0; j < 8; j++) s[j] = f2bf(src[j]);
    *(ushort8_t*)(o + (long)row * 192 + sc * 8) = s;
}

// ---------------------------------------------------------------------------
// conv1x1 via bf16 MFMA, round 5: round-0 shape (128-px tile, 48x64 wave
// tiles, 96-row W chunks double-buffered) but W staged via async
// global_load_lds from pre-swizzled bf16 (no register staging, no staging
// VALU, balanced swizzled ds_reads). X staged once as before (pad 200).
// ---------------------------------------------------------------------------
__global__ __launch_bounds__(256) void k_conv_mfma(
    const float* __restrict__ in,            // [4][192][N_PIX] f32
    const unsigned short* __restrict__ wswz, // [576][192] bf16, swizzled
    unsigned short* __restrict__ out)        // [4][576][N_PIX] bf16
{
    const int p0 = blockIdx.x * 128;
    const int b  = blockIdx.y;
    const float* inb = in + (long)b * 192 * N_PIX;
    unsigned short* ob = out + (long)b * 576 * N_PIX;

    __shared__ unsigned short Xl[128 * 200];       // 51.2 KB, pad-200 layout
    __shared__ unsigned short Wl[2][96 * 192];     // 73.7 KB, linear+swizzle

    const int tid  = threadIdx.x;
    const int lane = tid & 63;
    const int wid  = tid >> 6;
    const int wo   = wid >> 1;
    const int wp   = wid & 1;
    const int l15  = lane & 15;
    const int lq   = lane >> 4;

    // issue chunk 0 DMA first so it overlaps the X staging loads.
    // chunk = 96 rows * 384 B = 36864 B; per wave 9216 B = 9 x 1024 B.
    {
        const long cb = (long)wid * 9216;
        #pragma unroll
        for (int it = 0; it < 9; it++) {
            glds16(wswz + (cb + it * 1024) / 2 + lane * 8,
                   &Wl[0][(cb + it * 1024) / 2]);
        }
    }

    {   // stage X tile transposed [p][k], f32 -> bf16 (round-0 pattern)
        const int p = tid & 127, kh = tid >> 7;
        #pragma unroll
        for (int seg = 0; seg < 12; seg++) {
            ushort8_t pk;
            #pragma unroll
            for (int j = 0; j < 8; j++)
                pk[j] = f2bf(inb[(long)(kh * 96 + seg * 8 + j) * N_PIX + p0 + p]);
            *(ushort8_t*)&Xl[p * 200 + kh * 96 + seg * 8] = pk;
        }
    }
    __syncthreads();   // drains vmcnt: chunk 0 in LDS, X staged

    #pragma unroll 1
    for (int oc = 0; oc < 6; oc++) {
        if (oc + 1 < 6) {   // prefetch next W chunk into alternate buffer
            const long gb = (long)(oc + 1) * 36864 + (long)wid * 9216;
            unsigned short* lb = &Wl[(oc + 1) & 1][wid * 4608];
            #pragma unroll
            for (int it = 0; it < 9; it++)
                glds16(wswz + (gb + it * 1024) / 2 + lane * 8, lb + it * 512);
        }
        const unsigned short* Wb = Wl[oc & 1];
        f32x4 acc[3][4];
        const f32x4 zero = {0.f, 0.f, 0.f, 0.f};
        #pragma unroll
        for (int i = 0; i < 3; i++)
            #pragma unroll
            for (int j = 0; j < 4; j++) acc[i][j] = zero;

        #pragma unroll
        for (int kc = 0; kc < 6; kc++) {
            bf16x8 af[3], bfv[4];
            #pragma unroll
            for (int mt = 0; mt < 3; mt++) {
                const int row = wo * 48 + mt * 16 + l15;
                const int sc  = (kc * 4 + lq) ^ (l15 & 7);   // de-swizzle
                af[mt] = *(const bf16x8*)&Wb[row * 192 + sc * 8];
            }
            #pragma unroll
            for (int nt = 0; nt < 4; nt++)
                bfv[nt] = *(const bf16x8*)&Xl[(wp * 64 + nt * 16 + l15) * 200 + kc * 32 + lq * 8];
            #pragma unroll
            for (int mt = 0; mt < 3; mt++)
                #pragma unroll
                for (int nt = 0; nt < 4; nt++)
                    acc[mt][nt] = __builtin_amdgcn_mfma_f32_16x16x32_bf16(
                        af[mt], bfv[nt], acc[mt][nt], 0, 0, 0);
        }
        #pragma unroll
        for (int mt = 0; mt < 3; mt++) {
            #pragma unroll
            for (int r = 0; r < 4; r++) {
                int o = oc * 96 + wo * 48 + mt * 16 + lq * 4 + r;
                long base = (long)o * N_PIX + p0 + wp * 64 + l15;
                #pragma unroll
                for (int nt = 0; nt < 4; nt++)
                    ob[base + nt * 16] = f2bf(acc[mt][nt][r]);
            }
        }
        __syncthreads();   // all waves done with Wl[oc&1]; chunk oc+1 arrived
    }
}

// ---------------------------------------------------------------------------
// depthwise 3x3, pad 1, bf16 -> bf16, vectorized (unchanged)
// ---------------------------------------------------------------------------
__global__ __launch_bounds__(256) void k_dwconv(
    const unsigned short* __restrict__ in, const float* __restrict__ w,
    unsigned short* __restrict__ out)
{
    const int m  = blockIdx.y;              // b*576 + ch
    const int ch = m % 576;
    const int y0 = blockIdx.x * 16;
    const unsigned short* ip = in + (long)m * N_PIX;
    const float* wp = w + ch * 9;

    __shared__ unsigned short Ll[18][136];

    const int tid = threadIdx.x;
    #pragma unroll
    for (int idx = tid; idx < 288; idx += 256) {
        int lr = idx >> 4, lc = (idx & 15) * 8;
        int gy = y0 - 1 + lr;
        ushort8_t v;
        #pragma unroll
        for (int j = 0; j < 8; j++) v[j] = 0;
        if ((unsigned)gy <= 127u)
            v = *(const ushort8_t*)(ip + gy * W_ + lc);
        *(ushort8_t*)&Ll[lr][lc] = v;
    }
    float wv[9];
    #pragma unroll
    for (int i = 0; i < 9; i++) wv[i] = wp[i];
    __syncthreads();

    const int r  = tid >> 4;
    const int xg = (tid & 15) * 8;

    float o[8];
    #pragma unroll
    for (int j = 0; j < 8; j++) o[j] = 0.f;

    #pragma unroll
    for (int dy = 0; dy < 3; dy++) {
        const unsigned short* lrow = &Ll[r + dy][0];
        float c[10];
        c[0] = (xg == 0) ? 0.f : bf2f(lrow[xg - 1]);
        ushort8_t mid = *(const ushort8_t*)&lrow[xg];
        #pragma unroll
        for (int j = 0; j < 8; j++) c[1 + j] = bf2f(mid[j]);
        c[9] = (xg == 120) ? 0.f : bf2f(lrow[xg + 8]);
        const float w0 = wv[dy * 3], w1 = wv[dy * 3 + 1], w2 = wv[dy * 3 + 2];
        #pragma unroll
        for (int j = 0; j < 8; j++)
            o[j] = fmaf(w0, c[j], fmaf(w1, c[j + 1], fmaf(w2, c[j + 2], o[j])));
    }
    ushort8_t res;
    #pragma unroll
    for (int j = 0; j < 8; j++) res[j] = f2bf(o[j]);
    *(ushort8_t*)(out + (long)m * N_PIX + (y0 + r) * W_ + xg) = res;
}

// ---------------------------------------------------------------------------
// gram + norms via MFMA (unchanged)
// ---------------------------------------------------------------------------
__global__ __launch_bounds__(256) void k_gram_mfma(
    const unsigned short* __restrict__ qkv_x,
    const unsigned short* __restrict__ qkv_c,
    float* __restrict__ S, float* __restrict__ qn, float* __restrict__ kn)
{
    const int attn = blockIdx.z;
    const int bh   = blockIdx.y;
    const int b = bh >> 2, h = bh & 3;
    const unsigned short* qb =
        (attn == 0 ? qkv_x : qkv_c) + ((long)b * 576 + h * 48) * N_PIX;
    const unsigned short* kb =
        (attn == 0 ? qkv_c : qkv_x) + ((long)b * 576 + 192 + h * 48) * N_PIX;

    __shared__ float Sl[48 * 49];
    __shared__ float qnl[48], knl[48];

    const int tid = threadIdx.x;
    for (int i = tid; i < 48 * 49; i += 256) Sl[i] = 0.f;
    if (tid < 48) { qnl[tid] = 0.f; knl[tid] = 0.f; }
    __syncthreads();

    const int lane = tid & 63, wid = tid >> 6;
    const int l15 = lane & 15, lq = lane >> 4;
    const long nbase = (long)blockIdx.x * 1024 + wid * 256;

    f32x4 acc[3][3], aq[3], ak[3];
    const f32x4 zero = {0.f, 0.f, 0.f, 0.f};
    #pragma unroll
    for (int i = 0; i < 3; i++) {
        aq[i] = zero; ak[i] = zero;
        #pragma unroll
        for (int j = 0; j < 3; j++) acc[i][j] = zero;
    }

    for (int ks = 0; ks < 8; ks++) {
        const long ns = nbase + ks * 32;
        bf16x8 af[3], bfv[3];
        #pragma unroll
        for (int mt = 0; mt < 3; mt++)
            af[mt] = *(const bf16x8*)(qb + (long)(mt * 16 + l15) * N_PIX + ns + lq * 8);
        #pragma unroll
        for (int nt = 0; nt < 3; nt++)
            bfv[nt] = *(const bf16x8*)(kb + (long)(nt * 16 + l15) * N_PIX + ns + lq * 8);
        #pragma unroll
        for (int mt = 0; mt < 3; mt++)
            #pragma unroll
            for (int nt = 0; nt < 3; nt++)
                acc[mt][nt] = __builtin_amdgcn_mfma_f32_16x16x32_bf16(
                    af[mt], bfv[nt], acc[mt][nt], 0, 0, 0);
        #pragma unroll
        for (int mt = 0; mt < 3; mt++)
            aq[mt] = __builtin_amdgcn_mfma_f32_16x16x32_bf16(af[mt], af[mt], aq[mt], 0, 0, 0);
        #pragma unroll
        for (int nt = 0; nt < 3; nt++)
            ak[nt] = __builtin_amdgcn_mfma_f32_16x16x32_bf16(bfv[nt], bfv[nt], ak[nt], 0, 0, 0);
    }

    #pragma unroll
    for (int mt = 0; mt < 3; mt++)
        #pragma unroll
        for (int nt = 0; nt < 3; nt++)
            #pragma unroll
            for (int r = 0; r < 4; r++)
                atomicAdd(&Sl[(mt * 16 + lq * 4 + r) * 49 + nt * 16 + l15],
                          acc[mt][nt][r]);
    #pragma unroll
    for (int mt = 0; mt < 3; mt++)
        #pragma unroll
        for (int r = 0; r < 4; r++)
            if (l15 == lq * 4 + r) {
                atomicAdd(&qnl[mt * 16 + l15], aq[mt][r]);
                atomicAdd(&knl[mt * 16 + l15], ak[mt][r]);
            }
    __syncthreads();

    float* Sg = S + (long)(attn * 16 + bh) * 2304;
    float* qg = qn + (long)(attn * 16 + bh) * 48;
    float* kg = kn + (long)(attn * 16 + bh) * 48;
    for (int i = tid; i < 2304; i += 256) {
        int row = i / 48, col = i - row * 48;
        atomicAdd(&Sg[i], Sl[row * 49 + col]);
    }
    if (tid < 48) atomicAdd(&qg[tid], qnl[tid]);
    else if (tid < 96) atomicAdd(&kg[tid - 48], knl[tid - 48]);
}

// ---------------------------------------------------------------------------
// softmax (unchanged)
// ---------------------------------------------------------------------------
__global__ __launch_bounds__(192) void k_softmax(
    const float* __restrict__ S, const float* __restrict__ qn,
    const float* __restrict__ kn, const float* __restrict__ temp,
    float* __restrict__ P)
{
    const int attn = blockIdx.x, b = blockIdx.y;
    const int r = threadIdx.x;
    const int h = r / 48, c = r % 48;
    const int bh = b * 4 + h;
    const float t = temp[h];
    const float* Srow = S + ((long)(attn * 16 + bh) * 48 + c) * 48;
    const float* knp  = kn + (long)(attn * 16 + bh) * 48;
    const float qc = fmaxf(sqrtf(qn[(long)(attn * 16 + bh) * 48 + c]), 1e-12f);
    float lg[48];
    float mx = -1e30f;
    #pragma unroll
    for (int d = 0; d < 48; d++) {
        float kd = fmaxf(sqrtf(knp[d]), 1e-12f);
        lg[d] = Srow[d] / (qc * kd) * t;
        mx = fmaxf(mx, lg[d]);
    }
    float sum = 0.f;
    #pragma unroll
    for (int d = 0; d < 48; d++) { lg[d] = __expf(lg[d] - mx); sum += lg[d]; }
    const float inv = 1.f / sum;
    float* Pp = P + (((long)(attn * 4 + b) * 4 + h) * 48 + c) * 48;
    #pragma unroll
    for (int d = 0; d < 48; d++) Pp[d] = lg[d] * inv;
}

// ---------------------------------------------------------------------------
// W2[attn][b][o][h*48+d] = sum_c po[o][h*48+c] * P[attn][b][h][c][d]  (bf16)
// ---------------------------------------------------------------------------
__global__ __launch_bounds__(192) void k_w2(
    const float* __restrict__ P, const float* __restrict__ x_po,
    const float* __restrict__ ctx_po, unsigned short* __restrict__ W2)
{
    const int h = blockIdx.x, b = blockIdx.y, attn = blockIdx.z;
    const float* po = (attn == 0) ? ctx_po : x_po;
    __shared__ float Pl[48][48];
    const float* Pp = P + ((long)(attn * 4 + b) * 4 + h) * 2304;
    for (int it = 0; it < 12; it++) {
        int idx = it * 192 + threadIdx.x;
        Pl[idx / 48][idx % 48] = Pp[idx];
    }
    __syncthreads();
    const int o = threadIdx.x;
    float acc[48];
    #pragma unroll
    for (int d = 0; d < 48; d++) acc[d] = 0.f;
    for (int c = 0; c < 48; c++) {
        float pv = po[(long)o * 192 + h * 48 + c];
        #pragma unroll
        for (int d = 0; d < 48; d++)
            acc[d] = fmaf(pv, Pl[c][d], acc[d]);
    }
    unsigned short* wp = W2 + ((long)(attn * 4 + b) * 192 + o) * 192 + h * 48;
    #pragma unroll
    for (int d = 0; d < 48; d++) wp[d] = f2bf(acc[d]);
}

// ---------------------------------------------------------------------------
// final GEMM via MFMA (round-0 form: 128-px tile, W2 from global, grid(128,8))
// ---------------------------------------------------------------------------
__global__ __launch_bounds__(256) void k_gemm_v(
    const unsigned short* __restrict__ qkv_x,
    const unsigned short* __restrict__ qkv_c,
    const unsigned short* __restrict__ W2bf,   // [attn][b][192][192] bf16
    float* __restrict__ out)
{
    const int p0 = blockIdx.x * 128;
    const int z  = blockIdx.y;
    const int br = z >> 2, b = z & 3;
    const unsigned short* v =
        (br == 0 ? qkv_x : qkv_c) + (long)b * 576 * N_PIX + 384L * N_PIX;
    const unsigned short* wb =
        W2bf + ((long)((br == 0 ? 1 : 0) * 4 + b)) * 36864;
    float* ob = out + (long)br * 12582912 + (long)b * 192 * N_PIX;

    __shared__ unsigned short Xl[128 * 200];

    const int tid  = threadIdx.x;
    const int lane = tid & 63;
    const int wid  = tid >> 6;
    const int wo   = wid >> 1;
    const int wp   = wid & 1;
    const int l15  = lane & 15;
    const int lq   = lane >> 4;

    {   // stage V tile transposed [p][k]
        const int p = tid & 127, kh = tid >> 7;
        #pragma unroll
        for (int seg = 0; seg < 12; seg++) {
            ushort8_t pk;
            #pragma unroll
            for (int j = 0; j < 8; j++)
                pk[j] = v[(long)(kh * 96 + seg * 8 + j) * N_PIX + p0 + p];
            *(ushort8_t*)&Xl[p * 200 + kh * 96 + seg * 8] = pk;
        }
    }
    __syncthreads();

    #pragma unroll
    for (int oc = 0; oc < 2; oc++) {
        f32x4 acc[3][4];
        const f32x4 zero = {0.f, 0.f, 0.f, 0.f};
        #pragma unroll
        for (int i = 0; i < 3; i++)
            #pragma unroll
            for (int j = 0; j < 4; j++) acc[i][j] = zero;

        #pragma unroll
        for (int kc = 0; kc < 6; kc++) {
            bf16x8 af[3], bfv[4];
            #pragma unroll
            for (int mt = 0; mt < 3; mt++)
                af[mt] = *(const bf16x8*)(wb +
                    (long)(oc * 96 + wo * 48 + mt * 16 + l15) * 192 + kc * 32 + lq * 8);
            #pragma unroll
            for (int nt = 0; nt < 4; nt++)
                bfv[nt] = *(const bf16x8*)&Xl[(wp * 64 + nt * 16 + l15) * 200 + kc * 32 + lq * 8];
            #pragma unroll
            for (int mt = 0; mt < 3; mt++)
                #pragma unroll
                for (int nt = 0; nt < 4; nt++)
                    acc[mt][nt] = __builtin_amdgcn_mfma_f32_16x16x32_bf16(
                        af[mt], bfv[nt], acc[mt][nt], 0, 0, 0);
        }
        #pragma unroll
        for (int mt = 0; mt < 3; mt++) {
            #pragma unroll
            for (int r = 0; r < 4; r++) {
                int o = oc * 96 + wo * 48 + mt * 16 + lq * 4 + r;
                long base = (long)o * N_PIX + p0 + wp * 64 + l15;
                #pragma unroll
                for (int nt = 0; nt < 4; nt++)
                    ob[base + nt * 16] = acc[mt][nt][r];
            }
        }
    }
}

// ---------------------------------------------------------------------------
extern "C" void kernel_launch(void* const* d_in, const int* in_sizes, int n_in,
                              void* d_out, int out_size, void* d_ws, size_t ws_size,
                              hipStream_t stream) {
    (void)in_sizes; (void)n_in; (void)out_size; (void)ws_size;
    const float* x       = (const float*)d_in[0];
    const float* ctx     = (const float*)d_in[1];
    const float* x_qkv_w = (const float*)d_in[2];
    const float* x_dw_w  = (const float*)d_in[3];
    const float* x_po_w  = (const float*)d_in[4];
    const float* c_qkv_w = (const float*)d_in[5];
    const float* c_dw_w  = (const float*)d_in[6];
    const float* c_po_w  = (const float*)d_in[7];
    const float* temp    = (const float*)d_in[8];
    float* out = (float*)d_out;

    const long QKV = 37748736L;                  // 4*576*16384 elements
    unsigned short* qkv_x16 = (unsigned short*)d_ws;
    unsigned short* qkv_c16 = qkv_x16 + QKV;
    float* S  = (float*)(qkv_c16 + QKV);         // 2*16*48*48
    float* qn = S + 73728;
    float* kn = qn + 1536;
    float* P  = kn + 1536;
    unsigned short* W2bf = (unsigned short*)(P + 73728);   // 2*4*192*192 bf16

    hipMemsetAsync(S, 0, (73728 + 1536 + 1536) * sizeof(float), stream);

    // conv tmp (bf16) lives in d_out: fully overwritten by k_gemm_v afterwards.
    // swizzled bf16 conv weights live in the unused tail of d_out (75.5 MB
    // used by tmp16, 100.7 MB total; consumed before k_gemm_v overwrites).
    unsigned short* tmp16 = (unsigned short*)d_out;
    unsigned short* wx16  = (unsigned short*)d_out + QKV;
    unsigned short* wc16  = wx16 + 110592;

    k_pack_w_swz<<<dim3(54), 256, 0, stream>>>(x_qkv_w, wx16);
    k_pack_w_swz<<<dim3(54), 256, 0, stream>>>(c_qkv_w, wc16);

    k_conv_mfma<<<dim3(128, 4), 256, 0, stream>>>(x, wx16, tmp16);
    k_dwconv<<<dim3(8, 2304), 256, 0, stream>>>(tmp16, x_dw_w, qkv_x16);
    k_conv_mfma<<<dim3(128, 4), 256, 0, stream>>>(ctx, c_qkv_w != 0 ? wc16 : wc16, tmp16);
    k_dwconv<<<dim3(8, 2304), 256, 0, stream>>>(tmp16, c_dw_w, qkv_c16);

    k_gram_mfma<<<dim3(16, 16, 2), 256, 0, stream>>>(qkv_x16, qkv_c16, S, qn, kn);
    k_softmax<<<dim3(2, 4), dim3(192), 0, stream>>>(S, qn, kn, temp, P);
    k_w2<<<dim3(4, 4, 2), dim3(192), 0, stream>>>(P, x_po_w, c_po_w, W2bf);

    k_gemm_v<<<dim3(128, 8), 256, 0, stream>>>(qkv_x16, qkv_c16, W2bf, out);
}